// Round 7
// baseline (130.852 us; speedup 1.0000x reference)
//
#include <hip/hip_runtime.h>

// Sparse voxel downsample (FACTOR=2, RES=256 -> res=128, B=2, C=64).
// code = ((b*128 + x/2)*128 + y/2)*128 + z/2  in [0, 4194304)
// u8 dense histogram + 2-level packed (flag,count) scan -> sorted rank AND
// row_start per unique code (== jnp.unique order). Counting-sort the INDICES
// by rank, then a gather hot pass: sequential NT writes, random 256B NT reads
// with 8 chains in flight per quarter-wave, in-register mean (no atomics).

#define RES2 128
#define NCODES (2 * 128 * 128 * 128)   // 4194304 codes
#define NW (NCODES / 4)                // u32 words in u8 histogram
#define HBLK 4096                      // blocks over code space (1024 codes)

typedef unsigned long long u64;
typedef float f4 __attribute__((ext_vector_type(4)));   // NT-compatible float4

__global__ void count_codes(const int* __restrict__ coords,
                            unsigned* __restrict__ cnt8,
                            int* __restrict__ codes, int n) {
    int i = blockIdx.x * 256 + threadIdx.x;
    if (i >= n) return;
    const int4 v = reinterpret_cast<const int4*>(coords)[i];
    int code = (((v.x * RES2 + (v.y >> 1)) * RES2 + (v.z >> 1)) * RES2) + (v.w >> 1);
    codes[i] = code;
    atomicAdd(&cnt8[code >> 2], 1u << (8 * (code & 3)));   // u8 lanes, max ~9
}

// Per block of 1024 codes: packed (count_sum<<32 | flag_sum).
__global__ void block_sums(const unsigned* __restrict__ cnt8,
                           u64* __restrict__ btot) {
    __shared__ u64 sh[256];
    int t = threadIdx.x;
    unsigned w = cnt8[blockIdx.x * 256 + t];
    unsigned c0 = w & 0xFFu, c1 = (w >> 8) & 0xFFu,
             c2 = (w >> 16) & 0xFFu, c3 = w >> 24;
    u64 s = ((u64)(c0 + c1 + c2 + c3) << 32) |
            (u64)((c0 != 0) + (c1 != 0) + (c2 != 0) + (c3 != 0));
    sh[t] = s;
    __syncthreads();
    for (int off = 128; off > 0; off >>= 1) {
        if (t < off) sh[t] += sh[t + off];
        __syncthreads();
    }
    if (t == 0) btot[blockIdx.x] = sh[0];
}

// Single block: exclusive scan over 4096 packed totals; n_unique -> *nuq.
__global__ void scan_totals(u64* __restrict__ btot, unsigned* __restrict__ nuq) {
    __shared__ u64 sh[1024];
    int t = threadIdx.x;
    int base = t * 4;
    u64 v[4], e[4], s = 0;
#pragma unroll
    for (int j = 0; j < 4; ++j) { v[j] = btot[base + j]; e[j] = s; s += v[j]; }
    sh[t] = s;
    __syncthreads();
    for (int off = 1; off < 1024; off <<= 1) {
        u64 add = (t >= off) ? sh[t - off] : 0ull;
        __syncthreads();
        sh[t] += add;
        __syncthreads();
    }
    u64 excl = (t == 0) ? 0ull : sh[t - 1];
#pragma unroll
    for (int j = 0; j < 4; ++j) btot[base + j] = excl + e[j];
    if (t == 1023) *nuq = (unsigned)(sh[1023] & 0xFFFFFFFFull);
}

// Second pass: per-block packed scan + base -> for each occupied code:
// rank_tab[code] = rank;  uniq_cc[rank] = code | cnt<<22;
// row_end[rank] = row_start (fill pass increments it to row_end).
__global__ void scan_write(const unsigned* __restrict__ cnt8,
                           const u64* __restrict__ btot,
                           unsigned* __restrict__ rank_tab,
                           unsigned* __restrict__ uniq_cc,
                           unsigned* __restrict__ row_end) {
    __shared__ u64 sh[256];
    int t = threadIdx.x;
    unsigned w = cnt8[blockIdx.x * 256 + t];
    unsigned c4[4] = {w & 0xFFu, (w >> 8) & 0xFFu, (w >> 16) & 0xFFu, w >> 24};
    u64 e[4], s = 0;
#pragma unroll
    for (int j = 0; j < 4; ++j) {
        e[j] = s;
        s += ((u64)c4[j] << 32) | (u64)(c4[j] != 0);
    }
    sh[t] = s;
    __syncthreads();
    for (int off = 1; off < 256; off <<= 1) {
        u64 add = (t >= off) ? sh[t - off] : 0ull;
        __syncthreads();
        sh[t] += add;
        __syncthreads();
    }
    u64 texcl = ((t == 0) ? 0ull : sh[t - 1]) + btot[blockIdx.x];
    int cbase = (blockIdx.x * 256 + t) * 4;
#pragma unroll
    for (int j = 0; j < 4; ++j) {
        if (c4[j]) {
            unsigned r = (unsigned)((texcl + e[j]) & 0xFFFFFFFFull);
            unsigned st = (unsigned)((texcl + e[j]) >> 32);
            int code = cbase + j;
            rank_tab[code] = r;
            uniq_cc[r] = (unsigned)code | (c4[j] << 22);
            row_end[r] = st;
        }
    }
}

// Counting sort of indices by rank. After this, row_end[r] = start+cnt.
__global__ void fill_sorted(const int* __restrict__ codes,
                            const unsigned* __restrict__ rank_tab,
                            unsigned* __restrict__ row_end,
                            int* __restrict__ sorted_idx, int n) {
    int i = blockIdx.x * 256 + threadIdx.x;
    if (i >= n) return;
    unsigned r = rank_tab[codes[i]];
    unsigned pos = atomicAdd(&row_end[r], 1u);
    sorted_idx[pos] = i;
}

// Hot pass: 32 output rows per wave (quarter-wave = one 256B row, 8 batches).
// All 8 load chains issued before any store; sequential NT writes.
__global__ void gather32(const f4* __restrict__ feats4,
                         const int* __restrict__ sorted_idx,
                         const unsigned* __restrict__ row_end,
                         const unsigned* __restrict__ uniq_cc,
                         const unsigned* __restrict__ nuq_p,
                         f4* __restrict__ outF4,
                         f4* __restrict__ outC4, int n) {
    int tid = blockIdx.x * 256 + threadIdx.x;
    int wave = tid >> 6;
    int lane = threadIdx.x & 63;
    int q = lane >> 4;
    int sub = lane & 15;
    int rb = wave * 32 + q;
    int nuq = (int)*nuq_p;

    if (rb + 28 < nuq) {   // fast path: all 8 rows valid
        int r[8];
        unsigned en[8], cc[8];
#pragma unroll
        for (int k = 0; k < 8; ++k) r[k] = rb + k * 4;
#pragma unroll
        for (int k = 0; k < 8; ++k) en[k] = row_end[r[k]];
#pragma unroll
        for (int k = 0; k < 8; ++k) cc[k] = uniq_cc[r[k]];
        int cnt[8], st[8], i0[8];
#pragma unroll
        for (int k = 0; k < 8; ++k) {
            cnt[k] = (int)(cc[k] >> 22);
            st[k] = (int)en[k] - cnt[k];
        }
#pragma unroll
        for (int k = 0; k < 8; ++k) i0[k] = sorted_idx[st[k]];
        f4 a[8];
#pragma unroll
        for (int k = 0; k < 8; ++k)
            a[k] = __builtin_nontemporal_load(&feats4[(size_t)i0[k] * 16 + sub]);
#pragma unroll
        for (int k = 0; k < 8; ++k) {
            if (cnt[k] > 1) {
                for (int m = 1; m < cnt[k]; ++m) {
                    int i = sorted_idx[st[k] + m];
                    f4 v = __builtin_nontemporal_load(&feats4[(size_t)i * 16 + sub]);
                    a[k] += v;
                }
                a[k] *= (1.0f / (float)cnt[k]);
            }
            __builtin_nontemporal_store(a[k], &outF4[(size_t)r[k] * 16 + sub]);
            if (sub == 0) {
                unsigned code = cc[k] & 0x3FFFFFu;
                f4 cv = {(float)(code >> 21), (float)((code >> 14) & 127),
                         (float)((code >> 7) & 127), (float)(code & 127)};
                __builtin_nontemporal_store(cv, &outC4[r[k]]);
            }
        }
    } else {
#pragma unroll
        for (int k = 0; k < 8; ++k) {
            int r = rb + k * 4;
            if (r >= n) continue;
            if (r < nuq) {
                unsigned en = row_end[r];
                unsigned cc = uniq_cc[r];
                int cnt = (int)(cc >> 22);
                int st = (int)en - cnt;
                f4 a = {0.f, 0.f, 0.f, 0.f};
                for (int m = 0; m < cnt; ++m) {
                    int i = sorted_idx[st + m];
                    a += feats4[(size_t)i * 16 + sub];
                }
                a *= (1.0f / (float)cnt);
                outF4[(size_t)r * 16 + sub] = a;
                if (sub == 0) {
                    unsigned code = cc & 0x3FFFFFu;
                    f4 cv = {(float)(code >> 21), (float)((code >> 14) & 127),
                             (float)((code >> 7) & 127), (float)(code & 127)};
                    outC4[r] = cv;
                }
            } else {
                f4 zz = {0.f, 0.f, 0.f, 0.f};
                outF4[(size_t)r * 16 + sub] = zz;
                if (sub == 0) {
                    f4 mm = {-1.f, -1.f, -1.f, -1.f};
                    outC4[r] = mm;
                }
            }
        }
    }
}

extern "C" void kernel_launch(void* const* d_in, const int* in_sizes, int n_in,
                              void* d_out, int out_size, void* d_ws, size_t ws_size,
                              hipStream_t stream) {
    const float* feats = (const float*)d_in[0];
    const int* coords = (const int*)d_in[1];
    const int n = in_sizes[1] / 4;   // N = 500000

    float* outF = (float*)d_out;
    f4* outC4 = (f4*)(outF + (size_t)n * 64);

    unsigned* cnt8 = (unsigned*)d_ws;              // NW u32 (4.19 MB)
    u64* btot = (u64*)(cnt8 + NW);                 // 4096 u64
    unsigned* nuq = (unsigned*)(btot + HBLK);      // 1 (+1 pad)
    int* codes = (int*)(nuq + 2);                  // n
    unsigned* rank_tab = (unsigned*)(codes + n);   // NCODES u32 (16.8 MB)
    unsigned* uniq_cc = rank_tab + NCODES;         // n
    unsigned* row_end = uniq_cc + n;               // n
    int* sorted_idx = (int*)(row_end + n);         // n

    (void)hipMemsetAsync(cnt8, 0, (size_t)NW * sizeof(unsigned), stream);

    count_codes<<<(n + 255) / 256, 256, 0, stream>>>(coords, cnt8, codes, n);
    block_sums<<<HBLK, 256, 0, stream>>>(cnt8, btot);
    scan_totals<<<1, 1024, 0, stream>>>(btot, nuq);
    scan_write<<<HBLK, 256, 0, stream>>>(cnt8, btot, rank_tab, uniq_cc, row_end);
    fill_sorted<<<(n + 255) / 256, 256, 0, stream>>>(codes, rank_tab, row_end, sorted_idx, n);

    int waves = (n + 31) / 32;
    int blocks = (waves * 64 + 255) / 256;
    gather32<<<blocks, 256, 0, stream>>>((const f4*)feats, sorted_idx,
                                         row_end, uniq_cc, nuq,
                                         (f4*)outF, outC4, n);
}

// Round 8
// 119.614 us; speedup vs baseline: 1.0940x; 1.0940x over previous
//
#include <hip/hip_runtime.h>

// Sparse voxel downsample (FACTOR=2, RES=256 -> res=128, B=2, C=64).
// code = ((b*128 + x/2)*128 + y/2)*128 + z/2  in [0, 4194304)
// u8 dense histogram + 2-level packed (flag,count) scan -> sorted rank AND
// row_start per unique code (== jnp.unique order). Rank is re-derived from a
// per-word occupied-prefix (wprefix) instead of a 16.8MB rank table.
// Counting-sort the INDICES by rank, then a gather hot pass: sequential NT
// writes, random 256B regular reads (L3-resident feats), 8 chains in flight
// per quarter-wave, in-register mean (no feature atomics).

#define RES2 128
#define NCODES (2 * 128 * 128 * 128)   // 4194304 codes
#define NW (NCODES / 4)                // u32 words in u8 histogram
#define HBLK 4096                      // blocks over code space (1024 codes)

typedef unsigned long long u64;
typedef float f4 __attribute__((ext_vector_type(4)));   // NT-compatible float4

__global__ void count_codes(const int* __restrict__ coords,
                            unsigned* __restrict__ cnt8,
                            int* __restrict__ codes, int n) {
    int i = blockIdx.x * 256 + threadIdx.x;
    if (i >= n) return;
    const int4 v = reinterpret_cast<const int4*>(coords)[i];
    int code = (((v.x * RES2 + (v.y >> 1)) * RES2 + (v.z >> 1)) * RES2) + (v.w >> 1);
    codes[i] = code;
    atomicAdd(&cnt8[code >> 2], 1u << (8 * (code & 3)));   // u8 lanes, max ~9
}

// Per block of 1024 codes: packed (count_sum<<32 | flag_sum).
__global__ void block_sums(const unsigned* __restrict__ cnt8,
                           u64* __restrict__ btot) {
    __shared__ u64 sh[256];
    int t = threadIdx.x;
    unsigned w = cnt8[blockIdx.x * 256 + t];
    unsigned c0 = w & 0xFFu, c1 = (w >> 8) & 0xFFu,
             c2 = (w >> 16) & 0xFFu, c3 = w >> 24;
    u64 s = ((u64)(c0 + c1 + c2 + c3) << 32) |
            (u64)((c0 != 0) + (c1 != 0) + (c2 != 0) + (c3 != 0));
    sh[t] = s;
    __syncthreads();
    for (int off = 128; off > 0; off >>= 1) {
        if (t < off) sh[t] += sh[t + off];
        __syncthreads();
    }
    if (t == 0) btot[blockIdx.x] = sh[0];
}

// Single block: exclusive scan over 4096 packed totals; n_unique -> *nuq.
__global__ void scan_totals(u64* __restrict__ btot, unsigned* __restrict__ nuq) {
    __shared__ u64 sh[1024];
    int t = threadIdx.x;
    int base = t * 4;
    u64 v[4], e[4], s = 0;
#pragma unroll
    for (int j = 0; j < 4; ++j) { v[j] = btot[base + j]; e[j] = s; s += v[j]; }
    sh[t] = s;
    __syncthreads();
    for (int off = 1; off < 1024; off <<= 1) {
        u64 add = (t >= off) ? sh[t - off] : 0ull;
        __syncthreads();
        sh[t] += add;
        __syncthreads();
    }
    u64 excl = (t == 0) ? 0ull : sh[t - 1];
#pragma unroll
    for (int j = 0; j < 4; ++j) btot[base + j] = excl + e[j];
    if (t == 1023) *nuq = (unsigned)(sh[1023] & 0xFFFFFFFFull);
}

// Second pass: per-block packed scan + base. Per word: wprefix[w] = #occupied
// codes before word w (sequential 4MB write). Per occupied code:
// uniq_cc[rank] = code | cnt<<22;  row_end[rank] = row_start.
__global__ void scan_write(const unsigned* __restrict__ cnt8,
                           const u64* __restrict__ btot,
                           unsigned* __restrict__ wprefix,
                           unsigned* __restrict__ uniq_cc,
                           unsigned* __restrict__ row_end) {
    __shared__ u64 sh[256];
    int t = threadIdx.x;
    int widx = blockIdx.x * 256 + t;
    unsigned w = cnt8[widx];
    unsigned c4[4] = {w & 0xFFu, (w >> 8) & 0xFFu, (w >> 16) & 0xFFu, w >> 24};
    u64 e[4], s = 0;
#pragma unroll
    for (int j = 0; j < 4; ++j) {
        e[j] = s;
        s += ((u64)c4[j] << 32) | (u64)(c4[j] != 0);
    }
    sh[t] = s;
    __syncthreads();
    for (int off = 1; off < 256; off <<= 1) {
        u64 add = (t >= off) ? sh[t - off] : 0ull;
        __syncthreads();
        sh[t] += add;
        __syncthreads();
    }
    u64 texcl = ((t == 0) ? 0ull : sh[t - 1]) + btot[blockIdx.x];
    wprefix[widx] = (unsigned)(texcl & 0xFFFFFFFFull);
    int cbase = widx * 4;
#pragma unroll
    for (int j = 0; j < 4; ++j) {
        if (c4[j]) {
            unsigned r = (unsigned)((texcl + e[j]) & 0xFFFFFFFFull);
            unsigned st = (unsigned)((texcl + e[j]) >> 32);
            int code = cbase + j;
            uniq_cc[r] = (unsigned)code | (c4[j] << 22);
            row_end[r] = st;
        }
    }
}

// Counting sort of indices by rank (rank recomputed from cnt8 + wprefix).
// After this, row_end[r] = start+cnt.
__global__ void fill_sorted(const int* __restrict__ codes,
                            const unsigned* __restrict__ cnt8,
                            const unsigned* __restrict__ wprefix,
                            unsigned* __restrict__ row_end,
                            int* __restrict__ sorted_idx, int n) {
    int i = blockIdx.x * 256 + threadIdx.x;
    if (i >= n) return;
    int c = codes[i];
    unsigned w = cnt8[c >> 2];
    unsigned base = wprefix[c >> 2];
    int j = c & 3;
    unsigned occ = 0;
    if (j > 0) occ += ((w & 0xFFu) != 0);
    if (j > 1) occ += (((w >> 8) & 0xFFu) != 0);
    if (j > 2) occ += (((w >> 16) & 0xFFu) != 0);
    unsigned r = base + occ;
    unsigned pos = atomicAdd(&row_end[r], 1u);
    sorted_idx[pos] = i;
}

// Hot pass: 32 output rows per wave (quarter-wave = one 256B row, 8 batches).
// All 8 load chains issued before any store; regular loads (L3-warm feats),
// sequential NT writes (don't displace feats from L3).
__global__ void gather32(const f4* __restrict__ feats4,
                         const int* __restrict__ sorted_idx,
                         const unsigned* __restrict__ row_end,
                         const unsigned* __restrict__ uniq_cc,
                         const unsigned* __restrict__ nuq_p,
                         f4* __restrict__ outF4,
                         f4* __restrict__ outC4, int n) {
    int tid = blockIdx.x * 256 + threadIdx.x;
    int wave = tid >> 6;
    int lane = threadIdx.x & 63;
    int q = lane >> 4;
    int sub = lane & 15;
    int rb = wave * 32 + q;
    int nuq = (int)*nuq_p;

    if (rb + 28 < nuq) {   // fast path: all 8 rows valid
        int r[8];
        unsigned en[8], cc[8];
#pragma unroll
        for (int k = 0; k < 8; ++k) r[k] = rb + k * 4;
#pragma unroll
        for (int k = 0; k < 8; ++k) en[k] = row_end[r[k]];
#pragma unroll
        for (int k = 0; k < 8; ++k) cc[k] = uniq_cc[r[k]];
        int cnt[8], st[8], i0[8];
#pragma unroll
        for (int k = 0; k < 8; ++k) {
            cnt[k] = (int)(cc[k] >> 22);
            st[k] = (int)en[k] - cnt[k];
        }
#pragma unroll
        for (int k = 0; k < 8; ++k) i0[k] = sorted_idx[st[k]];
        f4 a[8];
#pragma unroll
        for (int k = 0; k < 8; ++k)
            a[k] = feats4[(size_t)i0[k] * 16 + sub];
#pragma unroll
        for (int k = 0; k < 8; ++k) {
            if (cnt[k] > 1) {
                for (int m = 1; m < cnt[k]; ++m) {
                    int i = sorted_idx[st[k] + m];
                    a[k] += feats4[(size_t)i * 16 + sub];
                }
                a[k] *= (1.0f / (float)cnt[k]);
            }
            __builtin_nontemporal_store(a[k], &outF4[(size_t)r[k] * 16 + sub]);
            if (sub == 0) {
                unsigned code = cc[k] & 0x3FFFFFu;
                f4 cv = {(float)(code >> 21), (float)((code >> 14) & 127),
                         (float)((code >> 7) & 127), (float)(code & 127)};
                __builtin_nontemporal_store(cv, &outC4[r[k]]);
            }
        }
    } else {
#pragma unroll
        for (int k = 0; k < 8; ++k) {
            int r = rb + k * 4;
            if (r >= n) continue;
            if (r < nuq) {
                unsigned en = row_end[r];
                unsigned cc = uniq_cc[r];
                int cnt = (int)(cc >> 22);
                int st = (int)en - cnt;
                f4 a = {0.f, 0.f, 0.f, 0.f};
                for (int m = 0; m < cnt; ++m) {
                    int i = sorted_idx[st + m];
                    a += feats4[(size_t)i * 16 + sub];
                }
                a *= (1.0f / (float)cnt);
                outF4[(size_t)r * 16 + sub] = a;
                if (sub == 0) {
                    unsigned code = cc & 0x3FFFFFu;
                    f4 cv = {(float)(code >> 21), (float)((code >> 14) & 127),
                             (float)((code >> 7) & 127), (float)(code & 127)};
                    outC4[r] = cv;
                }
            } else {
                f4 zz = {0.f, 0.f, 0.f, 0.f};
                outF4[(size_t)r * 16 + sub] = zz;
                if (sub == 0) {
                    f4 mm = {-1.f, -1.f, -1.f, -1.f};
                    outC4[r] = mm;
                }
            }
        }
    }
}

extern "C" void kernel_launch(void* const* d_in, const int* in_sizes, int n_in,
                              void* d_out, int out_size, void* d_ws, size_t ws_size,
                              hipStream_t stream) {
    const float* feats = (const float*)d_in[0];
    const int* coords = (const int*)d_in[1];
    const int n = in_sizes[1] / 4;   // N = 500000

    float* outF = (float*)d_out;
    f4* outC4 = (f4*)(outF + (size_t)n * 64);

    unsigned* cnt8 = (unsigned*)d_ws;              // NW u32 (4.19 MB)
    u64* btot = (u64*)(cnt8 + NW);                 // 4096 u64
    unsigned* nuq = (unsigned*)(btot + HBLK);      // 1 (+1 pad)
    int* codes = (int*)(nuq + 2);                  // n
    unsigned* wprefix = (unsigned*)(codes + n);    // NW u32 (4.19 MB)
    unsigned* uniq_cc = wprefix + NW;              // n
    unsigned* row_end = uniq_cc + n;               // n
    int* sorted_idx = (int*)(row_end + n);         // n

    (void)hipMemsetAsync(cnt8, 0, (size_t)NW * sizeof(unsigned), stream);

    count_codes<<<(n + 255) / 256, 256, 0, stream>>>(coords, cnt8, codes, n);
    block_sums<<<HBLK, 256, 0, stream>>>(cnt8, btot);
    scan_totals<<<1, 1024, 0, stream>>>(btot, nuq);
    scan_write<<<HBLK, 256, 0, stream>>>(cnt8, btot, wprefix, uniq_cc, row_end);
    fill_sorted<<<(n + 255) / 256, 256, 0, stream>>>(codes, cnt8, wprefix, row_end, sorted_idx, n);

    int waves = (n + 31) / 32;
    int blocks = (waves * 64 + 255) / 256;
    gather32<<<blocks, 256, 0, stream>>>((const f4*)feats, sorted_idx,
                                         row_end, uniq_cc, nuq,
                                         (f4*)outF, outC4, n);
}